// Round 4
// baseline (40.128 us; speedup 1.0000x reference)
//
#include <hip/hip_runtime.h>

// GaussianSpot: out[k,b,i,j] = h/(2*pi*w^2) * exp(-0.5*((i-sx)^2+(j-sy)^2)/w^2)
// Separable: = [scale*exp2(c*(i-sx)^2)] * [exp2(c*(j-sy)^2)],  c = -0.5*log2(e)/w^2
// K=2, B=100000, D=14 -> 200000 spots x 196 px = 39.2M f32 (156.8 MB streamed write).
//
// R3: same as R2 (25 spots/block -> 8000 blocks for round-pipelining of the
// gather+exp prologue under streaming stores; nontemporal stores), with the
// nontemporal store fixed to use a native ext_vector type (HIP float4 is a
// class type that __builtin_nontemporal_store rejects).

typedef float f32x4 __attribute__((ext_vector_type(4)));

#define S_SPOTS 25
#define NBLK    (200000 / S_SPOTS)   // 8000 blocks
#define B_NUM   100000u
#define F_NUM   500
#define D_DIM   14u
#define LSTRIDE 16u                  // padded LDS row stride

__global__ __launch_bounds__(256) void gspot_kernel(
    const float* __restrict__ height,
    const float* __restrict__ width,
    const float* __restrict__ xoff,
    const float* __restrict__ yoff,
    const float* __restrict__ tlocs,   // [N, F, 2]
    const int*   __restrict__ n_idx,   // [B]
    const int*   __restrict__ f_idx,   // [B]
    f32x4*       __restrict__ out)
{
    __shared__ float sp_sx[S_SPOTS], sp_sy[S_SPOTS], sp_c[S_SPOTS], sp_sc[S_SPOTS];
    __shared__ float ex[S_SPOTS * LSTRIDE];
    __shared__ float ey[S_SPOTS * LSTRIDE];

    const float HALF_LOG2E = 0.7213475204444817f;   // 0.5 * log2(e)
    const float INV_2PI    = 0.15915494309189535f;  // 1 / (2*pi)

    const unsigned tid = threadIdx.x;
    const unsigned spot_base = blockIdx.x * S_SPOTS;

    // ---- Stage A: per-spot params (gather chain ONCE per spot) ----
    if (tid < S_SPOTS) {
        unsigned spot = spot_base + tid;
        unsigned b    = spot % B_NUM;           // k*B+b layout
        float h  = height[spot];
        float w  = width[spot];
        float sx = xoff[spot];
        float sy = yoff[spot];
        int n = n_idx[b];
        int f = f_idx[b];
        const float* tl = tlocs + ((unsigned)(n * F_NUM + f)) * 2u;
        sx += tl[0];
        sy += tl[1];
        float inv = __builtin_amdgcn_rcpf(w * w);
        sp_sx[tid] = sx;
        sp_sy[tid] = sy;
        sp_c[tid]  = -HALF_LOG2E * inv;
        sp_sc[tid] = h * inv * INV_2PI;
    }
    __syncthreads();

    // ---- Stage B: 1D exponentials, 28 per spot ----
    for (unsigned item = tid; item < S_SPOTS * 2u * D_DIM; item += 256u) {
        unsigned sp = item / (2u * D_DIM);      // magic-mul
        unsigned r  = item - sp * (2u * D_DIM);
        float c = sp_c[sp];
        if (r < D_DIM) {
            float d = (float)r - sp_sx[sp];
            ex[sp * LSTRIDE + r] = sp_sc[sp] * __builtin_amdgcn_exp2f(c * d * d);
        } else {
            unsigned j = r - D_DIM;
            float d = (float)j - sp_sy[sp];
            ey[sp * LSTRIDE + j] = __builtin_amdgcn_exp2f(c * d * d);
        }
    }
    __syncthreads();

    // ---- Stage C: pure streaming stores: e[i,j] = ex[i]*ey[j] ----
    f32x4* outb = out + (size_t)spot_base * 49u;
    for (unsigned idx = tid; idx < S_SPOTS * 49u; idx += 256u) {
        unsigned sp = idx / 49u;                // magic-mul
        unsigned q  = idx - sp * 49u;
        unsigned p0 = q * 4u;
        const float* exb = ex + sp * LSTRIDE;
        const float* eyb = ey + sp * LSTRIDE;
        f32x4 e;
        #pragma unroll
        for (int m = 0; m < 4; ++m) {
            unsigned p = p0 + (unsigned)m;      // pixel 0..195
            unsigned i = p / D_DIM;             // magic-mul
            unsigned j = p - i * D_DIM;
            e[m] = exb[i] * eyb[j];
        }
        __builtin_nontemporal_store(e, &outb[idx]);
    }
}

extern "C" void kernel_launch(void* const* d_in, const int* in_sizes, int n_in,
                              void* d_out, int out_size, void* d_ws, size_t ws_size,
                              hipStream_t stream) {
    const float* height = (const float*)d_in[0];
    const float* width  = (const float*)d_in[1];
    const float* x      = (const float*)d_in[2];
    const float* y      = (const float*)d_in[3];
    const float* tlocs  = (const float*)d_in[4];
    const int*   n_idx  = (const int*)d_in[5];
    const int*   f_idx  = (const int*)d_in[6];
    f32x4* out = (f32x4*)d_out;

    hipLaunchKernelGGL(gspot_kernel, dim3(NBLK), dim3(256), 0, stream,
                       height, width, x, y, tlocs, n_idx, f_idx, out);
}

// Round 5
// 34.543 us; speedup vs baseline: 1.1617x; 1.1617x over previous
//
#include <hip/hip_runtime.h>

// GaussianSpot: out[k,b,i,j] = h/(2*pi*w^2) * exp(-0.5*((i-sx)^2+(j-sy)^2)/w^2)
// Separable: = [scale*exp2(c*(i-sx)^2)] * [exp2(c*(j-sy)^2)],  c = -0.5*log2(e)/w^2
// K=2, B=100000, D=14 -> 200000 spots x 196 px = 39.2M f32 (156.8 MB streamed write).
//
// R4: A/B vs R3 — SAME 25-spot / 8000-block config, but nontemporal store
// reverted to a plain store (R3 regressed 33->40 with two confounded changes;
// this isolates which one hurt).

typedef float f32x4 __attribute__((ext_vector_type(4)));

#define S_SPOTS 25
#define NBLK    (200000 / S_SPOTS)   // 8000 blocks, ~3.9 rounds per residency slot
#define B_NUM   100000u
#define F_NUM   500
#define D_DIM   14u
#define LSTRIDE 16u                  // padded LDS row stride

__global__ __launch_bounds__(256) void gspot_kernel(
    const float* __restrict__ height,
    const float* __restrict__ width,
    const float* __restrict__ xoff,
    const float* __restrict__ yoff,
    const float* __restrict__ tlocs,   // [N, F, 2]
    const int*   __restrict__ n_idx,   // [B]
    const int*   __restrict__ f_idx,   // [B]
    f32x4*       __restrict__ out)
{
    __shared__ float sp_sx[S_SPOTS], sp_sy[S_SPOTS], sp_c[S_SPOTS], sp_sc[S_SPOTS];
    __shared__ float ex[S_SPOTS * LSTRIDE];
    __shared__ float ey[S_SPOTS * LSTRIDE];

    const float HALF_LOG2E = 0.7213475204444817f;   // 0.5 * log2(e)
    const float INV_2PI    = 0.15915494309189535f;  // 1 / (2*pi)

    const unsigned tid = threadIdx.x;
    const unsigned spot_base = blockIdx.x * S_SPOTS;

    // ---- Stage A: per-spot params (gather chain ONCE per spot) ----
    if (tid < S_SPOTS) {
        unsigned spot = spot_base + tid;
        unsigned b    = spot % B_NUM;           // k*B+b layout
        float h  = height[spot];
        float w  = width[spot];
        float sx = xoff[spot];
        float sy = yoff[spot];
        int n = n_idx[b];
        int f = f_idx[b];
        const float* tl = tlocs + ((unsigned)(n * F_NUM + f)) * 2u;
        sx += tl[0];
        sy += tl[1];
        float inv = __builtin_amdgcn_rcpf(w * w);
        sp_sx[tid] = sx;
        sp_sy[tid] = sy;
        sp_c[tid]  = -HALF_LOG2E * inv;
        sp_sc[tid] = h * inv * INV_2PI;
    }
    __syncthreads();

    // ---- Stage B: 1D exponentials, 28 per spot ----
    for (unsigned item = tid; item < S_SPOTS * 2u * D_DIM; item += 256u) {
        unsigned sp = item / (2u * D_DIM);      // magic-mul
        unsigned r  = item - sp * (2u * D_DIM);
        float c = sp_c[sp];
        if (r < D_DIM) {
            float d = (float)r - sp_sx[sp];
            ex[sp * LSTRIDE + r] = sp_sc[sp] * __builtin_amdgcn_exp2f(c * d * d);
        } else {
            unsigned j = r - D_DIM;
            float d = (float)j - sp_sy[sp];
            ey[sp * LSTRIDE + j] = __builtin_amdgcn_exp2f(c * d * d);
        }
    }
    __syncthreads();

    // ---- Stage C: pure streaming stores: e[i,j] = ex[i]*ey[j] ----
    f32x4* outb = out + (size_t)spot_base * 49u;
    for (unsigned idx = tid; idx < S_SPOTS * 49u; idx += 256u) {
        unsigned sp = idx / 49u;                // magic-mul
        unsigned q  = idx - sp * 49u;
        unsigned p0 = q * 4u;
        const float* exb = ex + sp * LSTRIDE;
        const float* eyb = ey + sp * LSTRIDE;
        f32x4 e;
        #pragma unroll
        for (int m = 0; m < 4; ++m) {
            unsigned p = p0 + (unsigned)m;      // pixel 0..195
            unsigned i = p / D_DIM;             // magic-mul
            unsigned j = p - i * D_DIM;
            e[m] = exb[i] * eyb[j];
        }
        outb[idx] = e;                           // plain store (nt reverted)
    }
}

extern "C" void kernel_launch(void* const* d_in, const int* in_sizes, int n_in,
                              void* d_out, int out_size, void* d_ws, size_t ws_size,
                              hipStream_t stream) {
    const float* height = (const float*)d_in[0];
    const float* width  = (const float*)d_in[1];
    const float* x      = (const float*)d_in[2];
    const float* y      = (const float*)d_in[3];
    const float* tlocs  = (const float*)d_in[4];
    const int*   n_idx  = (const int*)d_in[5];
    const int*   f_idx  = (const int*)d_in[6];
    f32x4* out = (f32x4*)d_out;

    hipLaunchKernelGGL(gspot_kernel, dim3(NBLK), dim3(256), 0, stream,
                       height, width, x, y, tlocs, n_idx, f_idx, out);
}

// Round 6
// 32.263 us; speedup vs baseline: 1.2438x; 1.0707x over previous
//
#include <hip/hip_runtime.h>

// GaussianSpot: out[k,b,i,j] = h/(2*pi*w^2) * exp(-0.5*((i-sx)^2+(j-sy)^2)/w^2)
// Separable: = [scale*exp2(c*(i-sx)^2)] * [exp2(c*(j-sy)^2)],  c = -0.5*log2(e)/w^2
// K=2, B=100000, D=14 -> 200000 spots x 196 px = 39.2M f32 (156.8 MB streamed write).
//
// R5: back to the best geometry (100 spots/block, 2000 blocks, plain stores).
// Stage C restructured to a fixed-q mapping: q = tid%49 (f4 slot), spy = tid/49
// (spot group of 5). All pixel (i,j) decompositions and the 8 LDS addresses are
// loop-invariant; the 20-iteration spot loop fully unrolls so offsets become
// ds_read_b32 immediates. Hot loop: 8 ds_read + 4 mul + 1 store per 16 B
// (was ~39 VALU + 8 DS with per-pixel magic-divs).

typedef float f32x4 __attribute__((ext_vector_type(4)));

#define S_SPOTS 100
#define NBLK    (200000 / S_SPOTS)   // 2000 blocks
#define B_NUM   100000u
#define F_NUM   500
#define D_DIM   14u
#define LSTRIDE 16u                  // padded LDS row stride (floats)
#define GROUPS  5u                   // spot groups in stage C (245 active threads)
#define ITERS   (S_SPOTS / GROUPS)   // 20 spots per thread

__global__ __launch_bounds__(256) void gspot_kernel(
    const float* __restrict__ height,
    const float* __restrict__ width,
    const float* __restrict__ xoff,
    const float* __restrict__ yoff,
    const float* __restrict__ tlocs,   // [N, F, 2]
    const int*   __restrict__ n_idx,   // [B]
    const int*   __restrict__ f_idx,   // [B]
    f32x4*       __restrict__ out)
{
    __shared__ float sp_sx[S_SPOTS], sp_sy[S_SPOTS], sp_c[S_SPOTS], sp_sc[S_SPOTS];
    __shared__ float ex[S_SPOTS * LSTRIDE];
    __shared__ float ey[S_SPOTS * LSTRIDE];

    const float HALF_LOG2E = 0.7213475204444817f;   // 0.5 * log2(e)
    const float INV_2PI    = 0.15915494309189535f;  // 1 / (2*pi)

    const unsigned tid = threadIdx.x;
    const unsigned spot_base = blockIdx.x * S_SPOTS;

    // ---- Stage A: per-spot params (gather chain ONCE per spot) ----
    if (tid < S_SPOTS) {
        unsigned spot = spot_base + tid;
        unsigned b    = spot % B_NUM;           // k*B+b layout
        float h  = height[spot];
        float w  = width[spot];
        float sx = xoff[spot];
        float sy = yoff[spot];
        int n = n_idx[b];
        int f = f_idx[b];
        const float* tl = tlocs + ((unsigned)(n * F_NUM + f)) * 2u;
        sx += tl[0];
        sy += tl[1];
        float inv = __builtin_amdgcn_rcpf(w * w);
        sp_sx[tid] = sx;
        sp_sy[tid] = sy;
        sp_c[tid]  = -HALF_LOG2E * inv;
        sp_sc[tid] = h * inv * INV_2PI;
    }
    __syncthreads();

    // ---- Stage B: 1D exponentials, 28 per spot ----
    for (unsigned item = tid; item < S_SPOTS * 2u * D_DIM; item += 256u) {
        unsigned sp = item / (2u * D_DIM);      // magic-mul
        unsigned r  = item - sp * (2u * D_DIM);
        float c = sp_c[sp];
        if (r < D_DIM) {
            float d = (float)r - sp_sx[sp];
            ex[sp * LSTRIDE + r] = sp_sc[sp] * __builtin_amdgcn_exp2f(c * d * d);
        } else {
            unsigned j = r - D_DIM;
            float d = (float)j - sp_sy[sp];
            ey[sp * LSTRIDE + j] = __builtin_amdgcn_exp2f(c * d * d);
        }
    }
    __syncthreads();

    // ---- Stage C: fixed-q streaming stores: e[i,j] = ex[i]*ey[j] ----
    // Thread (q, spy) handles f4 slot q of spots spy, spy+5, ..., spy+95.
    // Store index = sp*49 + q; at it=0 that equals tid, stride 245 per iter
    // -> wave-contiguous stores. All LDS offsets loop-invariant; full unroll
    // folds the per-iteration +320B into ds_read offset immediates.
    if (tid < GROUPS * 49u) {
        const unsigned q   = tid % 49u;
        const unsigned spy = tid / 49u;
        const unsigned p0  = q * 4u;

        const unsigned i0 = (p0 + 0u) / D_DIM, j0 = (p0 + 0u) % D_DIM;
        const unsigned i1 = (p0 + 1u) / D_DIM, j1 = (p0 + 1u) % D_DIM;
        const unsigned i2 = (p0 + 2u) / D_DIM, j2 = (p0 + 2u) % D_DIM;
        const unsigned i3 = (p0 + 3u) / D_DIM, j3 = (p0 + 3u) % D_DIM;

        const float* px0 = &ex[spy * LSTRIDE + i0];
        const float* px1 = &ex[spy * LSTRIDE + i1];
        const float* px2 = &ex[spy * LSTRIDE + i2];
        const float* px3 = &ex[spy * LSTRIDE + i3];
        const float* py0 = &ey[spy * LSTRIDE + j0];
        const float* py1 = &ey[spy * LSTRIDE + j1];
        const float* py2 = &ey[spy * LSTRIDE + j2];
        const float* py3 = &ey[spy * LSTRIDE + j3];

        f32x4* op = out + (size_t)blockIdx.x * (S_SPOTS * 49u) + tid;

        #pragma unroll
        for (unsigned it = 0; it < ITERS; ++it) {
            const unsigned o = it * GROUPS * LSTRIDE;   // +80 floats = 320 B / iter
            f32x4 e;
            e.x = px0[o] * py0[o];
            e.y = px1[o] * py1[o];
            e.z = px2[o] * py2[o];
            e.w = px3[o] * py3[o];
            op[it * (GROUPS * 49u)] = e;                // +245 f4 = 3920 B / iter
        }
    }
}

extern "C" void kernel_launch(void* const* d_in, const int* in_sizes, int n_in,
                              void* d_out, int out_size, void* d_ws, size_t ws_size,
                              hipStream_t stream) {
    const float* height = (const float*)d_in[0];
    const float* width  = (const float*)d_in[1];
    const float* x      = (const float*)d_in[2];
    const float* y      = (const float*)d_in[3];
    const float* tlocs  = (const float*)d_in[4];
    const int*   n_idx  = (const int*)d_in[5];
    const int*   f_idx  = (const int*)d_in[6];
    f32x4* out = (f32x4*)d_out;

    hipLaunchKernelGGL(gspot_kernel, dim3(NBLK), dim3(256), 0, stream,
                       height, width, x, y, tlocs, n_idx, f_idx, out);
}